// Round 1
// baseline (487.996 us; speedup 1.0000x reference)
//
#include <hip/hip_runtime.h>
#include <math.h>

// ---------------------------------------------------------------------------
// seg_starts[s] = first element index whose map value >= s   (map is sorted)
// seg_starts[S] = V.  Every s in [0,S] is written exactly once.
// ---------------------------------------------------------------------------
__global__ void k_segstarts(const int* __restrict__ map, int* __restrict__ starts,
                            int V, int S) {
    int i = blockIdx.x * blockDim.x + threadIdx.x;
    if (i >= V) return;
    int cur  = map[i];
    int prev = (i == 0) ? -1 : map[i - 1];
    for (int s = prev + 1; s <= cur; ++s) starts[s] = i;
    if (i == V - 1) {
        for (int s = cur + 1; s <= S; ++s) starts[s] = V;
    }
}

// ---------------------------------------------------------------------------
// M[i][j]  = sum_h Wk[h][i] * Wv[h][j]      (M = W_key^T @ W_value, 128x128)
// Wt[i][o] = Wo[o][i]                       (W_out transposed)
// ---------------------------------------------------------------------------
__global__ void k_prep(const float* __restrict__ Wk, const float* __restrict__ Wv,
                       const float* __restrict__ Wo,
                       float* __restrict__ M, float* __restrict__ Wt) {
    int i = blockIdx.x;    // 0..127
    int j = threadIdx.x;   // 0..127
    float acc = 0.f;
#pragma unroll 8
    for (int h = 0; h < 128; ++h)
        acc += Wk[h * 128 + i] * Wv[h * 128 + j];   // Wk read is block-uniform
    M[i * 128 + j]  = acc;
    Wt[i * 128 + j] = Wo[j * 128 + i];
}

// ---------------------------------------------------------------------------
// Main fused kernel: one 64-lane wave per segment.
// Lane l owns columns 2l and 2l+1 of the 128-wide rows.
//  sweep1: mean embedding (rows from HBM, contiguous)
//  matvec: q = M^T * mean        (M rows coalesced float2, mean via readlane)
//  sweep2: scores + online softmax + weighted embedding sum (rows from L2)
//  matvec: out = W_out * e_tilde (Wt rows coalesced float2)
// ---------------------------------------------------------------------------
__device__ __forceinline__ float lane_bcast(float v, int srcLane) {
    return __uint_as_float(__builtin_amdgcn_readlane(__float_as_uint(v), srcLane));
}

__global__ __launch_bounds__(512) void k_main(const float* __restrict__ E,
                                              const int* __restrict__ starts,
                                              const float* __restrict__ M,
                                              const float* __restrict__ Wt,
                                              float* __restrict__ out, int S) {
    int wave = (int)((blockIdx.x * blockDim.x + threadIdx.x) >> 6);
    int lane = threadIdx.x & 63;
    if (wave >= S) return;
    const int s = wave;
    const int r0 = starts[s];
    const int r1 = starts[s + 1];
    const int n  = r1 - r0;
    float* orow = out + (size_t)s * 128;

    if (n == 0) {                       // empty segment -> zeros
        orow[2 * lane]     = 0.f;
        orow[2 * lane + 1] = 0.f;
        return;
    }

    const float* base = E + (size_t)r0 * 128 + 2 * lane;

    // ---- sweep 1: segment mean --------------------------------------------
    float a0 = 0.f, a1 = 0.f;
#pragma unroll 4
    for (int r = 0; r < n; ++r) {
        const float2 e = *(const float2*)(base + (size_t)r * 128);
        a0 += e.x; a1 += e.y;
    }
    const float inv_n = 1.0f / (float)n;
    a0 *= inv_n; a1 *= inv_n;           // ebar at cols 2l, 2l+1

    // ---- q = M^T ebar ------------------------------------------------------
    float q0 = 0.f, q1 = 0.f;
    for (int i = 0; i < 128; i += 2) {
        const float s0 = lane_bcast(a0, i >> 1);   // ebar[i]
        const float s1 = lane_bcast(a1, i >> 1);   // ebar[i+1]
        const float2 m0 = *(const float2*)(M + i * 128 + 2 * lane);
        const float2 m1 = *(const float2*)(M + (i + 1) * 128 + 2 * lane);
        q0 += s0 * m0.x + s1 * m1.x;
        q1 += s0 * m0.y + s1 * m1.y;
    }

    // ---- sweep 2: scores + online softmax + weighted sum ------------------
    float mx = -INFINITY, Z = 0.f, w0 = 0.f, w1 = 0.f;
#pragma unroll 2
    for (int r = 0; r < n; ++r) {
        const float2 e = *(const float2*)(base + (size_t)r * 128);
        float p = q0 * e.x + q1 * e.y;
        p += __shfl_xor(p, 1);
        p += __shfl_xor(p, 2);
        p += __shfl_xor(p, 4);
        p += __shfl_xor(p, 8);
        p += __shfl_xor(p, 16);
        p += __shfl_xor(p, 32);          // full 64-lane sum -> all lanes
        if (p > mx) {                    // wave-uniform branch
            const float c = __expf(mx - p);
            Z *= c; w0 *= c; w1 *= c;
            mx = p;
        }
        const float w = __expf(p - mx);
        Z  += w;
        w0 += w * e.x;
        w1 += w * e.y;
    }
    const float invZ = 1.0f / Z;
    w0 *= invZ; w1 *= invZ;             // e_tilde at cols 2l, 2l+1

    // ---- out = W_out e_tilde ----------------------------------------------
    float o0 = 0.f, o1 = 0.f;
    for (int i = 0; i < 128; i += 2) {
        const float s0 = lane_bcast(w0, i >> 1);
        const float s1 = lane_bcast(w1, i >> 1);
        const float2 t0 = *(const float2*)(Wt + i * 128 + 2 * lane);
        const float2 t1 = *(const float2*)(Wt + (i + 1) * 128 + 2 * lane);
        o0 += s0 * t0.x + s1 * t1.x;
        o1 += s0 * t0.y + s1 * t1.y;
    }
    orow[2 * lane]     = o0;
    orow[2 * lane + 1] = o1;
}

// ---------------------------------------------------------------------------
extern "C" void kernel_launch(void* const* d_in, const int* in_sizes, int n_in,
                              void* d_out, int out_size, void* d_ws, size_t ws_size,
                              hipStream_t stream) {
    const float* E   = (const float*)d_in[0];
    const int*   map = (const int*)d_in[1];
    const float* Wk  = (const float*)d_in[3];
    const float* Wv  = (const float*)d_in[4];
    const float* Wo  = (const float*)d_in[5];
    float* out = (float*)d_out;

    const int V = in_sizes[1];
    const int S = out_size / 128;

    char* ws = (char*)d_ws;
    int*   starts = (int*)ws;
    size_t off = (((size_t)(S + 1) * sizeof(int)) + 255) & ~(size_t)255;
    float* M  = (float*)(ws + off);
    float* Wt = M + 128 * 128;

    k_segstarts<<<(V + 255) / 256, 256, 0, stream>>>(map, starts, V, S);
    k_prep<<<128, 128, 0, stream>>>(Wk, Wv, Wo, M, Wt);

    const int waves_per_block = 8;               // 512 threads
    const int grid = (S + waves_per_block - 1) / waves_per_block;
    k_main<<<grid, 64 * waves_per_block, 0, stream>>>(E, starts, M, Wt, out, S);
}

// Round 2
// 443.469 us; speedup vs baseline: 1.1004x; 1.1004x over previous
//
#include <hip/hip_runtime.h>
#include <math.h>

// ---------------------------------------------------------------------------
// seg_starts[s] = first element index whose map value >= s   (map is sorted)
// ---------------------------------------------------------------------------
__global__ void k_segstarts(const int* __restrict__ map, int* __restrict__ starts,
                            int V, int S) {
    int i = blockIdx.x * blockDim.x + threadIdx.x;
    if (i >= V) return;
    int cur  = map[i];
    int prev = (i == 0) ? -1 : map[i - 1];
    for (int s = prev + 1; s <= cur; ++s) starts[s] = i;
    if (i == V - 1) {
        for (int s = cur + 1; s <= S; ++s) starts[s] = V;
    }
}

// ---------------------------------------------------------------------------
// M[i][j]  = sum_h Wk[h][i] * Wv[h][j]      (M = W_key^T @ W_value, 128x128)
// Wt[i][o] = Wo[o][i]                       (W_out transposed)
// ---------------------------------------------------------------------------
__global__ void k_prep(const float* __restrict__ Wk, const float* __restrict__ Wv,
                       const float* __restrict__ Wo,
                       float* __restrict__ M, float* __restrict__ Wt) {
    int i = blockIdx.x;    // 0..127
    int j = threadIdx.x;   // 0..127
    float acc = 0.f;
#pragma unroll 8
    for (int h = 0; h < 128; ++h)
        acc += Wk[h * 128 + i] * Wv[h * 128 + j];
    M[i * 128 + j]  = acc;
    Wt[i * 128 + j] = Wo[j * 128 + i];
}

// ---------------------------------------------------------------------------
// Fused main kernel. 256 threads = 4 waves; one wave per segment.
// Lane decomposition within a wave: a = lane>>3 (row 0..7), b = lane&7
// (16-float column slice). Rows are processed 8 at a time with coalesced
// float4 loads (2 cache lines per row per instruction).
// Phases (3 barriers):
//   1. per-wave mean  -> sA[wv][*]      (ebar)
//   2. block GEMM  q = ebar @ M  (M read ONCE per block, broadcast) -> sB
//   3. per-wave scores + online softmax + weighted sum (E reused from regs)
//      -> etilde -> sA[wv][*]
//   4. block GEMM  out = etilde @ Wt -> global
// ---------------------------------------------------------------------------
#define SPB 4          // segments (= waves) per block
#define LDSW 132       // padded row stride (floats) to avoid bank conflicts

__global__ __launch_bounds__(256, 4) void k_main(const float* __restrict__ E,
                                                 const int* __restrict__ starts,
                                                 const float* __restrict__ M,
                                                 const float* __restrict__ Wt,
                                                 float* __restrict__ out, int S) {
    __shared__ float sA[SPB][LDSW];
    __shared__ float sB[SPB][LDSW];

    const int tid  = threadIdx.x;
    const int wv   = tid >> 6;          // local segment 0..3
    const int lane = tid & 63;
    const int a    = lane >> 3;         // row-in-chunk 0..7
    const int b    = lane & 7;          // 16-float slice 0..7
    const int seg  = blockIdx.x * SPB + wv;

    int r0 = 0, n = 0;
    if (seg < S) { r0 = starts[seg]; n = starts[seg + 1] - r0; }
    const float* segb = E + (size_t)r0 * 128 + b * 4;   // + t*32 for t=0..3

    // ---------------- phase 1: segment mean --------------------------------
    float4 sum[4];
#pragma unroll
    for (int t = 0; t < 4; ++t) sum[t] = make_float4(0.f, 0.f, 0.f, 0.f);

    for (int c = 0; c < n; c += 8) {
        if (a < n - c) {
            const float* rp = segb + (size_t)(c + a) * 128;
#pragma unroll
            for (int t = 0; t < 4; ++t) {
                const float4 e = *(const float4*)(rp + t * 32);
                sum[t].x += e.x; sum[t].y += e.y; sum[t].z += e.z; sum[t].w += e.w;
            }
        }
    }
    {   // reduce across the 8 row-lanes (bits 3,4,5)
        float* sf = (float*)sum;
#pragma unroll
        for (int k = 0; k < 16; ++k) {
            float v = sf[k];
            v += __shfl_xor(v, 8);
            v += __shfl_xor(v, 16);
            v += __shfl_xor(v, 32);
            sf[k] = v;
        }
    }
    const float inv_n = (n > 0) ? (1.0f / (float)n) : 0.0f;
    if (a == 0) {
#pragma unroll
        for (int t = 0; t < 4; ++t) {
            float4 e;
            e.x = sum[t].x * inv_n; e.y = sum[t].y * inv_n;
            e.z = sum[t].z * inv_n; e.w = sum[t].w * inv_n;
            *(float4*)&sA[wv][b * 4 + t * 32] = e;
        }
    }
    __syncthreads();

    // ---------------- phase 2: q = ebar @ M  (block GEMM) ------------------
    {
        const int r  = tid & 3;         // segment row
        const int jp = tid >> 2;        // output column pair
        const float* Mc = M + 2 * jp;
        float q0 = 0.f, q1 = 0.f, q2 = 0.f, q3 = 0.f;
#pragma unroll 8
        for (int i = 0; i < 128; i += 2) {
            const float e0 = sA[r][i];
            const float e1 = sA[r][i + 1];
            const float2 m0 = *(const float2*)(Mc + (size_t)i * 128);
            const float2 m1 = *(const float2*)(Mc + (size_t)(i + 1) * 128);
            q0 += e0 * m0.x; q1 += e0 * m0.y;
            q2 += e1 * m1.x; q3 += e1 * m1.y;
        }
        *(float2*)&sB[r][2 * jp] = make_float2(q0 + q2, q1 + q3);
    }
    __syncthreads();

    // ---------------- phase 3: scores + online softmax + weighted sum ------
    float4 qf[4];
#pragma unroll
    for (int t = 0; t < 4; ++t) qf[t] = *(const float4*)&sB[wv][b * 4 + t * 32];

    float mx = -INFINITY, Z = 0.f;
    float4 acc[4];
#pragma unroll
    for (int t = 0; t < 4; ++t) acc[t] = make_float4(0.f, 0.f, 0.f, 0.f);

    for (int c = 0; c < n; c += 8) {
        const bool act = (a < n - c);
        float4 ev[4];
#pragma unroll
        for (int t = 0; t < 4; ++t) ev[t] = make_float4(0.f, 0.f, 0.f, 0.f);
        if (act) {
            const float* rp = segb + (size_t)(c + a) * 128;
#pragma unroll
            for (int t = 0; t < 4; ++t) ev[t] = *(const float4*)(rp + t * 32);
        }
        // partial dot over this lane's 16 columns
        float p = ev[0].x * qf[0].x + ev[0].y * qf[0].y + ev[0].z * qf[0].z + ev[0].w * qf[0].w
                + ev[1].x * qf[1].x + ev[1].y * qf[1].y + ev[1].z * qf[1].z + ev[1].w * qf[1].w
                + ev[2].x * qf[2].x + ev[2].y * qf[2].y + ev[2].z * qf[2].z + ev[2].w * qf[2].w
                + ev[3].x * qf[3].x + ev[3].y * qf[3].y + ev[3].z * qf[3].z + ev[3].w * qf[3].w;
        // full row dot: reduce across the 8 column-slice lanes (bits 0,1,2)
        p += __shfl_xor(p, 1);
        p += __shfl_xor(p, 2);
        p += __shfl_xor(p, 4);
        if (!act) p = -INFINITY;
        // chunk max (reduce across rows, bits 3,4,5 -> wave-uniform)
        float mc = p;
        mc = fmaxf(mc, __shfl_xor(mc, 8));
        mc = fmaxf(mc, __shfl_xor(mc, 16));
        mc = fmaxf(mc, __shfl_xor(mc, 32));
        if (mc > mx) {                 // wave-uniform rescale (rare after chunk 0)
            const float sc = __expf(mx - mc);
            Z *= sc;
#pragma unroll
            for (int t = 0; t < 4; ++t) {
                acc[t].x *= sc; acc[t].y *= sc; acc[t].z *= sc; acc[t].w *= sc;
            }
            mx = mc;
        }
        const float w = __expf(p - mx);          // 0 for inactive lanes
        float cs = w;
        cs += __shfl_xor(cs, 8);
        cs += __shfl_xor(cs, 16);
        cs += __shfl_xor(cs, 32);                // sum over rows (w uniform in b)
        Z += cs;
#pragma unroll
        for (int t = 0; t < 4; ++t) {
            acc[t].x += w * ev[t].x; acc[t].y += w * ev[t].y;
            acc[t].z += w * ev[t].z; acc[t].w += w * ev[t].w;
        }
    }
    const float invZ = (n > 0) ? (1.0f / Z) : 0.0f;
    {
        float* af = (float*)acc;
#pragma unroll
        for (int k = 0; k < 16; ++k) {
            float v = af[k] * invZ;
            v += __shfl_xor(v, 8);
            v += __shfl_xor(v, 16);
            v += __shfl_xor(v, 32);
            af[k] = v;
        }
    }
    if (a == 0) {
#pragma unroll
        for (int t = 0; t < 4; ++t)
            *(float4*)&sA[wv][b * 4 + t * 32] = acc[t];   // etilde
    }
    __syncthreads();

    // ---------------- phase 4: out = etilde @ Wt  (block GEMM) -------------
    {
        const int r  = tid & 3;
        const int jp = tid >> 2;
        const float* Wc = Wt + 2 * jp;
        float o0 = 0.f, o1 = 0.f, o2 = 0.f, o3 = 0.f;
#pragma unroll 8
        for (int i = 0; i < 128; i += 2) {
            const float e0 = sA[r][i];
            const float e1 = sA[r][i + 1];
            const float2 w0 = *(const float2*)(Wc + (size_t)i * 128);
            const float2 w1 = *(const float2*)(Wc + (size_t)(i + 1) * 128);
            o0 += e0 * w0.x; o1 += e0 * w0.y;
            o2 += e1 * w1.x; o3 += e1 * w1.y;
        }
        const int gs = blockIdx.x * SPB + r;
        if (gs < S)
            *(float2*)&out[(size_t)gs * 128 + 2 * jp] = make_float2(o0 + o2, o1 + o3);
    }
}

// ---------------------------------------------------------------------------
extern "C" void kernel_launch(void* const* d_in, const int* in_sizes, int n_in,
                              void* d_out, int out_size, void* d_ws, size_t ws_size,
                              hipStream_t stream) {
    const float* E   = (const float*)d_in[0];
    const int*   map = (const int*)d_in[1];
    const float* Wk  = (const float*)d_in[3];
    const float* Wv  = (const float*)d_in[4];
    const float* Wo  = (const float*)d_in[5];
    float* out = (float*)d_out;

    const int V = in_sizes[1];
    const int S = out_size / 128;

    char* ws = (char*)d_ws;
    int*   starts = (int*)ws;
    size_t off = (((size_t)(S + 1) * sizeof(int)) + 255) & ~(size_t)255;
    float* M  = (float*)(ws + off);
    float* Wt = M + 128 * 128;

    k_segstarts<<<(V + 255) / 256, 256, 0, stream>>>(map, starts, V, S);
    k_prep<<<128, 128, 0, stream>>>(Wk, Wv, Wo, M, Wt);

    const int grid = (S + SPB - 1) / SPB;
    k_main<<<grid, 256, 0, stream>>>(E, starts, M, Wt, out, S);
}

// Round 3
// 418.016 us; speedup vs baseline: 1.1674x; 1.0609x over previous
//
#include <hip/hip_runtime.h>
#include <math.h>

#define SC 256   // super-chunk rows staged in LDS by k_attn

// ---------------------------------------------------------------------------
__global__ void k_segstarts(const int* __restrict__ map, int* __restrict__ starts,
                            int V, int S) {
    int i = blockIdx.x * blockDim.x + threadIdx.x;
    if (i >= V) return;
    int cur  = map[i];
    int prev = (i == 0) ? -1 : map[i - 1];
    for (int s = prev + 1; s <= cur; ++s) starts[s] = i;
    if (i == V - 1) {
        for (int s = cur + 1; s <= S; ++s) starts[s] = V;
    }
}

// M[i][j] = sum_h Wk[h][i]*Wv[h][j] ;  Wt[i][o] = Wo[o][i]
__global__ void k_prep(const float* __restrict__ Wk, const float* __restrict__ Wv,
                       const float* __restrict__ Wo,
                       float* __restrict__ M, float* __restrict__ Wt) {
    int i = blockIdx.x;
    int j = threadIdx.x;
    float acc = 0.f;
#pragma unroll 8
    for (int h = 0; h < 128; ++h)
        acc += Wk[h * 128 + i] * Wv[h * 128 + j];
    M[i * 128 + j]  = acc;
    Wt[i * 128 + j] = Wo[j * 128 + i];
}

// ---------------------------------------------------------------------------
// k_means: one wave per segment, lane owns cols 2l,2l+1. Pure streamer:
// 8 independent float2 loads in flight, no shfl, no LDS, no barriers.
// ---------------------------------------------------------------------------
__global__ __launch_bounds__(256) void k_means(const float* __restrict__ E,
                                               const int* __restrict__ starts,
                                               float* __restrict__ ebar, int S) {
    const int wave = (int)((blockIdx.x * blockDim.x + threadIdx.x) >> 6);
    const int lane = threadIdx.x & 63;
    if (wave >= S) return;
    const int r0 = starts[wave];
    const int n  = starts[wave + 1] - r0;
    const float* p = E + (size_t)r0 * 128 + 2 * lane;

    float s00 = 0.f, s01 = 0.f, s10 = 0.f, s11 = 0.f;
    float s20 = 0.f, s21 = 0.f, s30 = 0.f, s31 = 0.f;
    int r = 0;
#pragma unroll 2
    for (; r + 4 <= n; r += 4) {
        const float2 e0 = *(const float2*)(p + (size_t)(r + 0) * 128);
        const float2 e1 = *(const float2*)(p + (size_t)(r + 1) * 128);
        const float2 e2 = *(const float2*)(p + (size_t)(r + 2) * 128);
        const float2 e3 = *(const float2*)(p + (size_t)(r + 3) * 128);
        s00 += e0.x; s01 += e0.y; s10 += e1.x; s11 += e1.y;
        s20 += e2.x; s21 += e2.y; s30 += e3.x; s31 += e3.y;
    }
    for (; r < n; ++r) {
        const float2 e = *(const float2*)(p + (size_t)r * 128);
        s00 += e.x; s01 += e.y;
    }
    const float inv = (n > 0) ? (1.0f / (float)n) : 0.0f;
    float2 o;
    o.x = (s00 + s10 + s20 + s30) * inv;
    o.y = (s01 + s11 + s21 + s31) * inv;
    *(float2*)(ebar + (size_t)wave * 128 + 2 * lane) = o;
}

// ---------------------------------------------------------------------------
// k_q: q[s][j] = sum_i ebar[s][i] * M[i][j].  4 segments per thread, M load
// coalesced + amortized 4x. Writes q into d_out (consumed+overwritten later).
// ---------------------------------------------------------------------------
__global__ __launch_bounds__(256) void k_q(const float* __restrict__ ebar,
                                           const float* __restrict__ M,
                                           float* __restrict__ q, int S) {
    const int j  = threadIdx.x & 127;
    const int g  = threadIdx.x >> 7;            // 0..1
    const int s0 = blockIdx.x * 8 + g * 4;
    // clamp row pointers for safe loads; stores are guarded
    const float* e0 = ebar + (size_t)min(s0 + 0, S - 1) * 128;
    const float* e1 = ebar + (size_t)min(s0 + 1, S - 1) * 128;
    const float* e2 = ebar + (size_t)min(s0 + 2, S - 1) * 128;
    const float* e3 = ebar + (size_t)min(s0 + 3, S - 1) * 128;
    float q0 = 0.f, q1 = 0.f, q2 = 0.f, q3 = 0.f;
#pragma unroll 8
    for (int i = 0; i < 128; ++i) {
        const float m = M[i * 128 + j];
        q0 += m * e0[i]; q1 += m * e1[i]; q2 += m * e2[i]; q3 += m * e3[i];
    }
    if (s0 + 0 < S) q[(size_t)(s0 + 0) * 128 + j] = q0;
    if (s0 + 1 < S) q[(size_t)(s0 + 1) * 128 + j] = q1;
    if (s0 + 2 < S) q[(size_t)(s0 + 2) * 128 + j] = q2;
    if (s0 + 3 < S) q[(size_t)(s0 + 3) * 128 + j] = q3;
}

// ---------------------------------------------------------------------------
// k_attn: one wave per segment (4 waves/block, no cross-wave sync).
//  pass A (per <=256-row super-chunk): 8 rows/chunk, 16 cols/lane float4
//    loads, 16 FMA + 3 shfl per chunk; raw scores -> LDS; per-lane max.
//  merge: 3 shfl max, online rescale of (Z, acc).
//  pass B: re-read segment rows (L2-hot) with 2 cols/lane; w = exp(s-mx)
//    broadcast-read from LDS; zero shfl. Z accumulated redundantly per-lane.
//  epilogue: etilde = acc/Z overwrites the q row in d_out.
// ---------------------------------------------------------------------------
__global__ __launch_bounds__(256) void k_attn(const float* __restrict__ E,
                                              const int* __restrict__ starts,
                                              float* __restrict__ qet, int S) {
    __shared__ float sc[4][SC];
    const int wv   = threadIdx.x >> 6;
    const int lane = threadIdx.x & 63;
    const int seg  = blockIdx.x * 4 + wv;
    if (seg >= S) return;
    const int r0 = starts[seg];
    const int n  = starts[seg + 1] - r0;
    float* qrow = qet + (size_t)seg * 128;
    if (n == 0) {
        *(float2*)(qrow + 2 * lane) = make_float2(0.f, 0.f);
        return;
    }
    const int a = lane >> 3;
    const int b = lane & 7;

    float4 qf[4];
#pragma unroll
    for (int t = 0; t < 4; ++t) qf[t] = *(const float4*)(qrow + b * 4 + t * 32);

    const float* baseA = E + (size_t)r0 * 128 + b * 4;
    const float* baseB = E + (size_t)r0 * 128 + 2 * lane;

    float mx = -INFINITY, Z = 0.f, a0 = 0.f, a1 = 0.f;

    for (int c0 = 0; c0 < n; c0 += SC) {
        const int c1 = min(c0 + SC, n);

        // ---- pass A: raw scores -> LDS, per-lane running max ----
        float ml = -INFINITY;
        for (int c = c0; c < c1; c += 8) {
            const int row = c + a;
            float p = 0.f;
            if (row < c1) {
                const float* rp = baseA + (size_t)row * 128;
                const float4 e0 = *(const float4*)(rp);
                const float4 e1 = *(const float4*)(rp + 32);
                const float4 e2 = *(const float4*)(rp + 64);
                const float4 e3 = *(const float4*)(rp + 96);
                p = e0.x * qf[0].x + e0.y * qf[0].y + e0.z * qf[0].z + e0.w * qf[0].w
                  + e1.x * qf[1].x + e1.y * qf[1].y + e1.z * qf[1].z + e1.w * qf[1].w
                  + e2.x * qf[2].x + e2.y * qf[2].y + e2.z * qf[2].z + e2.w * qf[2].w
                  + e3.x * qf[3].x + e3.y * qf[3].y + e3.z * qf[3].z + e3.w * qf[3].w;
            }
            p += __shfl_xor(p, 1);
            p += __shfl_xor(p, 2);
            p += __shfl_xor(p, 4);
            if (row < c1) {
                if (b == 0) sc[wv][row - c0] = p;
                ml = fmaxf(ml, p);
            }
        }
        ml = fmaxf(ml, __shfl_xor(ml, 8));
        ml = fmaxf(ml, __shfl_xor(ml, 16));
        ml = fmaxf(ml, __shfl_xor(ml, 32));

        // ---- online merge ----
        const float nm = fmaxf(mx, ml);
        const float scale = __expf(mx - nm);     // 0 when mx was -inf
        Z *= scale; a0 *= scale; a1 *= scale;
        mx = nm;

        // ---- pass B: weighted accumulation, zero shfl ----
#pragma unroll 2
        for (int r4 = c0; r4 < c1; r4 += 4) {
            const float4 s4 = *(const float4*)&sc[wv][r4 - c0];
            if (r4 + 0 < c1) {
                const float w = __expf(s4.x - mx);
                const float2 e = *(const float2*)(baseB + (size_t)(r4 + 0) * 128);
                Z += w; a0 += w * e.x; a1 += w * e.y;
            }
            if (r4 + 1 < c1) {
                const float w = __expf(s4.y - mx);
                const float2 e = *(const float2*)(baseB + (size_t)(r4 + 1) * 128);
                Z += w; a0 += w * e.x; a1 += w * e.y;
            }
            if (r4 + 2 < c1) {
                const float w = __expf(s4.z - mx);
                const float2 e = *(const float2*)(baseB + (size_t)(r4 + 2) * 128);
                Z += w; a0 += w * e.x; a1 += w * e.y;
            }
            if (r4 + 3 < c1) {
                const float w = __expf(s4.w - mx);
                const float2 e = *(const float2*)(baseB + (size_t)(r4 + 3) * 128);
                Z += w; a0 += w * e.x; a1 += w * e.y;
            }
        }
    }
    const float invZ = 1.0f / Z;
    *(float2*)(qrow + 2 * lane) = make_float2(a0 * invZ, a1 * invZ);
}

// ---------------------------------------------------------------------------
// k_out: out[s][j] = sum_i etilde[s][i] * Wt[i][j], in-place on d_out.
// 8 segments per block staged to LDS, 4 segments per thread.
// ---------------------------------------------------------------------------
__global__ __launch_bounds__(256) void k_out(const float* __restrict__ Wt,
                                             float* __restrict__ io, int S) {
    __shared__ float et[8][128];
    const int tid = threadIdx.x;
    const int s_base = blockIdx.x * 8;
    {
        const int idx  = tid * 4;
        const int srow = idx >> 7;
        const int scol = idx & 127;
        const int gs   = s_base + srow;
        float4 v = make_float4(0.f, 0.f, 0.f, 0.f);
        if (gs < S) v = *(const float4*)(io + (size_t)gs * 128 + scol);
        *(float4*)&et[srow][scol] = v;
    }
    __syncthreads();
    const int j = tid & 127;
    const int g = tid >> 7;
    float o0 = 0.f, o1 = 0.f, o2 = 0.f, o3 = 0.f;
#pragma unroll 8
    for (int i = 0; i < 128; ++i) {
        const float w = Wt[i * 128 + j];
        o0 += w * et[g * 4 + 0][i];
        o1 += w * et[g * 4 + 1][i];
        o2 += w * et[g * 4 + 2][i];
        o3 += w * et[g * 4 + 3][i];
    }
    if (s_base + g * 4 + 0 < S) io[(size_t)(s_base + g * 4 + 0) * 128 + j] = o0;
    if (s_base + g * 4 + 1 < S) io[(size_t)(s_base + g * 4 + 1) * 128 + j] = o1;
    if (s_base + g * 4 + 2 < S) io[(size_t)(s_base + g * 4 + 2) * 128 + j] = o2;
    if (s_base + g * 4 + 3 < S) io[(size_t)(s_base + g * 4 + 3) * 128 + j] = o3;
}

// ---------------------------------------------------------------------------
extern "C" void kernel_launch(void* const* d_in, const int* in_sizes, int n_in,
                              void* d_out, int out_size, void* d_ws, size_t ws_size,
                              hipStream_t stream) {
    const float* E   = (const float*)d_in[0];
    const int*   map = (const int*)d_in[1];
    const float* Wk  = (const float*)d_in[3];
    const float* Wv  = (const float*)d_in[4];
    const float* Wo  = (const float*)d_in[5];
    float* out = (float*)d_out;

    const int V = in_sizes[1];
    const int S = out_size / 128;

    char* ws = (char*)d_ws;
    int*   starts = (int*)ws;
    size_t off = (((size_t)(S + 1) * sizeof(int)) + 255) & ~(size_t)255;
    float* M    = (float*)(ws + off);
    float* Wt   = M + 128 * 128;
    float* ebar = Wt + 128 * 128;          // S*128 floats (~25.6 MB)

    k_segstarts<<<(V + 255) / 256, 256, 0, stream>>>(map, starts, V, S);
    k_prep<<<128, 128, 0, stream>>>(Wk, Wv, Wo, M, Wt);
    k_means<<<(S + 3) / 4, 256, 0, stream>>>(E, starts, ebar, S);
    k_q<<<(S + 7) / 8, 256, 0, stream>>>(ebar, M, out, S);     // q -> d_out
    k_attn<<<(S + 3) / 4, 256, 0, stream>>>(E, starts, out, S); // etilde -> d_out
    k_out<<<(S + 7) / 8, 256, 0, stream>>>(Wt, out, S);         // out in-place
}